// Round 3
// baseline (80.803 us; speedup 1.0000x reference)
//
#include <hip/hip_runtime.h>
#include <hip/hip_bf16.h>

// RoIAlign (aligned-corner variant), fixed shape:
//   features: (N=2, C=256, H=200, W=304) f32 NCHW, rois: (R,5) f32, scale f32
//   out: (R, 256, 7, 7) f32
// Pipeline: NCHW f32 -> NHWC bf16 transpose (ws), then coalesced gather.
#define C_ 256
#define H_ 200
#define W_ 304
#define AH 7
#define AW 7
#define KK (AH * AW)
#define SP 260  // gather LDS row pad (words): 16B-aligned rows for float4 writes

__device__ __forceinline__ float b2f(unsigned short s) {
    return __uint_as_float((unsigned int)s << 16);
}

// ---------- Kernel 1: NCHW f32 -> NHWC bf16 ----------
// Tile: 64 pixels x 128 channels, 256 threads.
// Load phase: float4 (4 px, 1 ch) -> cvt_pk bf16 -> LDS u32 pixel-pair packed,
//             ds_write_b64, bank = (2c+2q) -> 2-way (free, m136).
// Store phase: thread (cq=t>>4, pp0=t&15): 8 u32 reads (bank = 16cq+2j+pp ->
//             all 32 banks, conflict-free), repack halves -> two ushort8
//             (16B) stores, each lane = one full 64B line.
__global__ __launch_bounds__(256) void transpose_nchw_nhwc_bf16(
    const float* __restrict__ in, unsigned short* __restrict__ out) {
    __shared__ unsigned int tile[128][34];  // [ch][px-pair], 17408 B
    const int HW = H_ * W_;
    const int n  = blockIdx.z;
    const int p0 = blockIdx.x * 64;   // pixel tile origin
    const int c0 = blockIdx.y * 128;  // channel tile origin
    const float* inb = in + (size_t)n * C_ * HW;
    unsigned short* outb = out + (size_t)n * HW * C_;

    {   // load: lanes walk pixel-quads, convert to bf16 before LDS
        const int q  = threadIdx.x & 15;   // pixel quad 0..15
        const int r0 = threadIdx.x >> 4;   // 0..15
        #pragma unroll
        for (int i = 0; i < 8; ++i) {
            const int c = r0 + 16 * i;     // 0..127
            const float4 v = *(const float4*)&inb[(size_t)(c0 + c) * HW + p0 + 4 * q];
            const __hip_bfloat162 lo = __float22bfloat162_rn(make_float2(v.x, v.y));
            const __hip_bfloat162 hi = __float22bfloat162_rn(make_float2(v.z, v.w));
            unsigned int ulo, uhi;
            __builtin_memcpy(&ulo, &lo, 4);
            __builtin_memcpy(&uhi, &hi, 4);
            *(uint2*)&tile[c][2 * q] = make_uint2(ulo, uhi);
        }
    }
    __syncthreads();
    {   // store: repack pixel-pairs -> channel-contiguous ushort8
        const int pp0 = threadIdx.x & 15;  // pixel-pair base 0..15
        const int cq  = threadIdx.x >> 4;  // channel octet 0..15
        #pragma unroll
        for (int i = 0; i < 2; ++i) {
            const int pp = pp0 + 16 * i;   // 0..31 (pixels 2pp, 2pp+1)
            unsigned int u[8];
            #pragma unroll
            for (int j = 0; j < 8; ++j) u[j] = tile[8 * cq + j][pp];
            unsigned int pe[4], po[4];
            #pragma unroll
            for (int k = 0; k < 4; ++k) {
                pe[k] = (u[2 * k] & 0xFFFFu) | (u[2 * k + 1] << 16);
                po[k] = (u[2 * k] >> 16) | (u[2 * k + 1] & 0xFFFF0000u);
            }
            unsigned short* oA = &outb[(size_t)(p0 + 2 * pp) * C_ + c0 + 8 * cq];
            unsigned short* oB = oA + C_;
            *(uint4*)oA = make_uint4(pe[0], pe[1], pe[2], pe[3]);
            *(uint4*)oB = make_uint4(po[0], po[1], po[2], po[3]);
        }
    }
}

// ---------- Kernel 2: RoIAlign gather from NHWC bf16 ----------
// One block (4 waves) per ROI. Wave w: points k = w, w+4, ... Lane owns 4
// channels (ushort4 8B corner loads, 512B/corner/wave coalesced). Results
// staged f32 in LDS [49][SP] (float4 writes conflict-free), then float4
// coalesced copy to (R, C, 7, 7).
__global__ __launch_bounds__(256) void roialign_nhwc_bf16(
    const unsigned short* __restrict__ tf, const float* __restrict__ rois,
    const float* __restrict__ scale_ptr, float* __restrict__ out) {
    __shared__ float sout[KK * SP];  // 50960 B
    const int r    = blockIdx.x;
    const int wave = threadIdx.x >> 6;
    const int lane = threadIdx.x & 63;
    const int c4   = lane * 4;

    const float scale = scale_ptr[0];
    const float* roi = rois + (size_t)r * 5;
    const int   b  = (int)roi[0];
    const float x1 = roi[1] * scale;
    const float y1 = roi[2] * scale;
    const float x2 = roi[3] * scale;
    const float y2 = roi[4] * scale;
    const float roi_w = fmaxf(x2 - x1 + 1.0f, 0.0f);
    const float roi_h = fmaxf(y2 - y1 + 1.0f, 0.0f);
    const float bin_h = roi_h / (float)(AH - 1);
    const float bin_w = roi_w / (float)(AW - 1);
    const unsigned short* fb = tf + (size_t)b * (H_ * W_) * C_;

    #pragma unroll 2
    for (int k = wave; k < KK; k += 4) {
        const int ph = k / AW;
        const int pw = k - ph * AW;
        const float h  = y1 + (float)ph * bin_h;
        const float w  = x1 + (float)pw * bin_w;
        const float hs = fminf(fmaxf(floorf(h), 0.0f), (float)(H_ - 2));
        const float ws = fminf(fmaxf(floorf(w), 0.0f), (float)(W_ - 2));
        const float dh = h - hs;
        const float dw = w - ws;
        const int   yi = (int)hs;
        const int   xi = (int)ws;
        const bool  valid = (h >= 0.0f) && (h < (float)H_) &&
                            (w >= 0.0f) && (w < (float)W_);
        const unsigned short* p = fb + ((size_t)yi * W_ + xi) * C_ + c4;
        const ushort4 a00 = *(const ushort4*)p;
        const ushort4 a01 = *(const ushort4*)(p + C_);
        const ushort4 a10 = *(const ushort4*)(p + (size_t)W_ * C_);
        const ushort4 a11 = *(const ushort4*)(p + (size_t)W_ * C_ + C_);
        const float w00 = (1.0f - dh) * (1.0f - dw);
        const float w01 = (1.0f - dh) * dw;
        const float w10 = dh * (1.0f - dw);
        const float w11 = dh * dw;
        float4 v;
        v.x = b2f(a00.x) * w00 + b2f(a01.x) * w01 + b2f(a10.x) * w10 + b2f(a11.x) * w11;
        v.y = b2f(a00.y) * w00 + b2f(a01.y) * w01 + b2f(a10.y) * w10 + b2f(a11.y) * w11;
        v.z = b2f(a00.z) * w00 + b2f(a01.z) * w01 + b2f(a10.z) * w10 + b2f(a11.z) * w11;
        v.w = b2f(a00.w) * w00 + b2f(a01.w) * w01 + b2f(a10.w) * w10 + b2f(a11.w) * w11;
        if (!valid) { v.x = 0.0f; v.y = 0.0f; v.z = 0.0f; v.w = 0.0f; }
        *(float4*)&sout[k * SP + c4] = v;
    }
    __syncthreads();
    float* ob = out + (size_t)r * C_ * KK;
    const int nf4 = C_ * KK / 4;  // 3136
    for (int idx = threadIdx.x; idx < nf4; idx += 256) {
        const int f = 4 * idx;
        float4 v;
        #pragma unroll
        for (int e = 0; e < 4; ++e) {
            const int fe = f + e;
            const int c = fe / KK;       // const-div -> mulhi
            const int k = fe - c * KK;
            (&v.x)[e] = sout[k * SP + c];
        }
        *(float4*)&ob[f] = v;
    }
}

// ---------- Fallback: direct NCHW gather (if ws too small) ----------
__global__ __launch_bounds__(256) void roialign_nchw(
    const float* __restrict__ feat, const float* __restrict__ rois,
    const float* __restrict__ scale_ptr, float* __restrict__ out) {
    __shared__ float sout[C_ * KK];
    const int r = blockIdx.x;
    const int c = threadIdx.x;
    const float scale = scale_ptr[0];
    const float* roi = rois + (size_t)r * 5;
    const int   b  = (int)roi[0];
    const float x1 = roi[1] * scale;
    const float y1 = roi[2] * scale;
    const float x2 = roi[3] * scale;
    const float y2 = roi[4] * scale;
    const float roi_w = fmaxf(x2 - x1 + 1.0f, 0.0f);
    const float roi_h = fmaxf(y2 - y1 + 1.0f, 0.0f);
    const float bin_h = roi_h / (float)(AH - 1);
    const float bin_w = roi_w / (float)(AW - 1);
    const float* fb = feat + ((size_t)b * C_ + c) * (H_ * W_);

    for (int ph = 0; ph < AH; ++ph) {
        const float h  = y1 + (float)ph * bin_h;
        const float hs = fminf(fmaxf(floorf(h), 0.0f), (float)(H_ - 2));
        const float dh = h - hs;
        const int   yi = (int)hs;
        const bool  vh = (h >= 0.0f) && (h < (float)H_);
        #pragma unroll
        for (int pw = 0; pw < AW; ++pw) {
            const float w  = x1 + (float)pw * bin_w;
            const float ws = fminf(fmaxf(floorf(w), 0.0f), (float)(W_ - 2));
            const float dw = w - ws;
            const int   xi = (int)ws;
            const bool  valid = vh && (w >= 0.0f) && (w < (float)W_);
            const float v00 = fb[(size_t)yi * W_ + xi];
            const float v01 = fb[(size_t)yi * W_ + xi + 1];
            const float v10 = fb[(size_t)(yi + 1) * W_ + xi];
            const float v11 = fb[(size_t)(yi + 1) * W_ + xi + 1];
            float val = v00 * (1.0f - dh) * (1.0f - dw)
                      + v01 * (1.0f - dh) * dw
                      + v10 * dh * (1.0f - dw)
                      + v11 * dh * dw;
            sout[c * KK + ph * AW + pw] = valid ? val : 0.0f;
        }
    }
    __syncthreads();
    float* ob = out + (size_t)r * C_ * KK;
    #pragma unroll 4
    for (int i = threadIdx.x; i < C_ * KK; i += 256) ob[i] = sout[i];
}

extern "C" void kernel_launch(void* const* d_in, const int* in_sizes, int n_in,
                              void* d_out, int out_size, void* d_ws, size_t ws_size,
                              hipStream_t stream) {
    const float* feat  = (const float*)d_in[0];
    const float* rois  = (const float*)d_in[1];
    const float* scale = (const float*)d_in[2];
    float* out = (float*)d_out;

    const int R = in_sizes[1] / 5;                 // 2000
    const int N = in_sizes[0] / (C_ * H_ * W_);    // 2
    const size_t need = (size_t)N * C_ * H_ * W_ * sizeof(unsigned short);

    if (ws_size >= need) {
        unsigned short* tf = (unsigned short*)d_ws;
        dim3 tb(256);
        dim3 tg((H_ * W_) / 64, C_ / 128, N);      // 950 x 2 x 2
        hipLaunchKernelGGL(transpose_nchw_nhwc_bf16, tg, tb, 0, stream, feat, tf);
        hipLaunchKernelGGL(roialign_nhwc_bf16, dim3(R), dim3(256), 0, stream,
                           tf, rois, scale, out);
    } else {
        hipLaunchKernelGGL(roialign_nchw, dim3(R), dim3(256), 0, stream,
                           feat, rois, scale, out);
    }
}

// Round 5
// 79.234 us; speedup vs baseline: 1.0198x; 1.0198x over previous
//
#include <hip/hip_runtime.h>
#include <hip/hip_bf16.h>

// RoIAlign (aligned-corner variant), fixed shape:
//   features: (N=2, C=256, H=200, W=304) f32 NCHW, rois: (R,5) f32, scale f32
//   out: (R, 256, 7, 7) f32
// Pipeline: NCHW f32 -> NHWC bf16 transpose (ws), then coalesced gather.
#define C_ 256
#define H_ 200
#define W_ 304
#define AH 7
#define AW 7
#define KK (AH * AW)
#define SP 260  // gather LDS row pad (words): 16B-aligned rows for float4 writes

typedef float f32x4 __attribute__((ext_vector_type(4)));  // clang vec: ok for nontemporal builtins

__device__ __forceinline__ float b2f(unsigned short s) {
    return __uint_as_float((unsigned int)s << 16);
}

// ---------- Kernel 1: NCHW f32 -> NHWC bf16 ----------
// Tile: 64 pixels x 128 channels, 256 threads.
__global__ __launch_bounds__(256) void transpose_nchw_nhwc_bf16(
    const float* __restrict__ in, unsigned short* __restrict__ out) {
    __shared__ unsigned int tile[128][34];  // [ch][px-pair], 17408 B
    const int HW = H_ * W_;
    const int n  = blockIdx.z;
    const int p0 = blockIdx.x * 64;   // pixel tile origin
    const int c0 = blockIdx.y * 128;  // channel tile origin
    const float* inb = in + (size_t)n * C_ * HW;
    unsigned short* outb = out + (size_t)n * HW * C_;

    {   // load: lanes walk pixel-quads, convert to bf16 before LDS
        const int q  = threadIdx.x & 15;   // pixel quad 0..15
        const int r0 = threadIdx.x >> 4;   // 0..15
        #pragma unroll
        for (int i = 0; i < 8; ++i) {
            const int c = r0 + 16 * i;     // 0..127
            const f32x4 v = __builtin_nontemporal_load(
                (const f32x4*)&inb[(size_t)(c0 + c) * HW + p0 + 4 * q]);
            const __hip_bfloat162 lo = __float22bfloat162_rn(make_float2(v.x, v.y));
            const __hip_bfloat162 hi = __float22bfloat162_rn(make_float2(v.z, v.w));
            unsigned int ulo, uhi;
            __builtin_memcpy(&ulo, &lo, 4);
            __builtin_memcpy(&uhi, &hi, 4);
            *(uint2*)&tile[c][2 * q] = make_uint2(ulo, uhi);
        }
    }
    __syncthreads();
    {   // store: repack pixel-pairs -> channel-contiguous ushort8
        const int pp0 = threadIdx.x & 15;  // pixel-pair base 0..15
        const int cq  = threadIdx.x >> 4;  // channel octet 0..15
        #pragma unroll
        for (int i = 0; i < 2; ++i) {
            const int pp = pp0 + 16 * i;   // 0..31 (pixels 2pp, 2pp+1)
            unsigned int u[8];
            #pragma unroll
            for (int j = 0; j < 8; ++j) u[j] = tile[8 * cq + j][pp];
            unsigned int pe[4], po[4];
            #pragma unroll
            for (int k = 0; k < 4; ++k) {
                pe[k] = (u[2 * k] & 0xFFFFu) | (u[2 * k + 1] << 16);
                po[k] = (u[2 * k] >> 16) | (u[2 * k + 1] & 0xFFFF0000u);
            }
            unsigned short* oA = &outb[(size_t)(p0 + 2 * pp) * C_ + c0 + 8 * cq];
            unsigned short* oB = oA + C_;
            *(uint4*)oA = make_uint4(pe[0], pe[1], pe[2], pe[3]);
            *(uint4*)oB = make_uint4(po[0], po[1], po[2], po[3]);
        }
    }
}

// ---------- Kernel 2: RoIAlign gather from NHWC bf16 ----------
// One block (8 waves, 512 thr) per ROI. Wave w: points k = w, w+8, ...
// Lane owns 4 channels (ushort4 8B corner loads, 512B/corner/wave coalesced).
// Stage f32 in LDS [49][SP], then float4 nontemporal copy to (R, C, 7, 7).
__global__ __launch_bounds__(512) void roialign_nhwc_bf16(
    const unsigned short* __restrict__ tf, const float* __restrict__ rois,
    const float* __restrict__ scale_ptr, float* __restrict__ out) {
    __shared__ float sout[KK * SP];  // 50960 B -> 3 blocks/CU, 24 waves/CU
    const int r    = blockIdx.x;
    const int wave = threadIdx.x >> 6;
    const int lane = threadIdx.x & 63;
    const int c4   = lane * 4;

    const float scale = scale_ptr[0];
    const float* roi = rois + (size_t)r * 5;
    const int   b  = (int)roi[0];
    const float x1 = roi[1] * scale;
    const float y1 = roi[2] * scale;
    const float x2 = roi[3] * scale;
    const float y2 = roi[4] * scale;
    const float roi_w = fmaxf(x2 - x1 + 1.0f, 0.0f);
    const float roi_h = fmaxf(y2 - y1 + 1.0f, 0.0f);
    const float bin_h = roi_h / (float)(AH - 1);
    const float bin_w = roi_w / (float)(AW - 1);
    const unsigned short* fb = tf + (size_t)b * (H_ * W_) * C_;

    #pragma unroll 2
    for (int k = wave; k < KK; k += 8) {
        const int ph = k / AW;
        const int pw = k - ph * AW;
        const float h  = y1 + (float)ph * bin_h;
        const float w  = x1 + (float)pw * bin_w;
        const float hs = fminf(fmaxf(floorf(h), 0.0f), (float)(H_ - 2));
        const float ws = fminf(fmaxf(floorf(w), 0.0f), (float)(W_ - 2));
        const float dh = h - hs;
        const float dw = w - ws;
        const int   yi = (int)hs;
        const int   xi = (int)ws;
        const bool  valid = (h >= 0.0f) && (h < (float)H_) &&
                            (w >= 0.0f) && (w < (float)W_);
        const unsigned short* p = fb + ((size_t)yi * W_ + xi) * C_ + c4;
        const ushort4 a00 = *(const ushort4*)p;
        const ushort4 a01 = *(const ushort4*)(p + C_);
        const ushort4 a10 = *(const ushort4*)(p + (size_t)W_ * C_);
        const ushort4 a11 = *(const ushort4*)(p + (size_t)W_ * C_ + C_);
        const float w00 = (1.0f - dh) * (1.0f - dw);
        const float w01 = (1.0f - dh) * dw;
        const float w10 = dh * (1.0f - dw);
        const float w11 = dh * dw;
        float4 v;
        v.x = b2f(a00.x) * w00 + b2f(a01.x) * w01 + b2f(a10.x) * w10 + b2f(a11.x) * w11;
        v.y = b2f(a00.y) * w00 + b2f(a01.y) * w01 + b2f(a10.y) * w10 + b2f(a11.y) * w11;
        v.z = b2f(a00.z) * w00 + b2f(a01.z) * w01 + b2f(a10.z) * w10 + b2f(a11.z) * w11;
        v.w = b2f(a00.w) * w00 + b2f(a01.w) * w01 + b2f(a10.w) * w10 + b2f(a11.w) * w11;
        if (!valid) { v.x = 0.0f; v.y = 0.0f; v.z = 0.0f; v.w = 0.0f; }
        *(float4*)&sout[k * SP + c4] = v;
    }
    __syncthreads();
    float* ob = out + (size_t)r * C_ * KK;
    const int nf4 = C_ * KK / 4;  // 3136
    for (int idx = threadIdx.x; idx < nf4; idx += 512) {
        const int f = 4 * idx;
        f32x4 v;
        #pragma unroll
        for (int e = 0; e < 4; ++e) {
            const int fe = f + e;
            const int c = fe / KK;       // const-div -> mulhi
            const int k = fe - c * KK;
            v[e] = sout[k * SP + c];
        }
        __builtin_nontemporal_store(v, (f32x4*)&ob[f]);
    }
}

// ---------- Fallback: direct NCHW gather (if ws too small) ----------
__global__ __launch_bounds__(256) void roialign_nchw(
    const float* __restrict__ feat, const float* __restrict__ rois,
    const float* __restrict__ scale_ptr, float* __restrict__ out) {
    __shared__ float sout[C_ * KK];
    const int r = blockIdx.x;
    const int c = threadIdx.x;
    const float scale = scale_ptr[0];
    const float* roi = rois + (size_t)r * 5;
    const int   b  = (int)roi[0];
    const float x1 = roi[1] * scale;
    const float y1 = roi[2] * scale;
    const float x2 = roi[3] * scale;
    const float y2 = roi[4] * scale;
    const float roi_w = fmaxf(x2 - x1 + 1.0f, 0.0f);
    const float roi_h = fmaxf(y2 - y1 + 1.0f, 0.0f);
    const float bin_h = roi_h / (float)(AH - 1);
    const float bin_w = roi_w / (float)(AW - 1);
    const float* fb = feat + ((size_t)b * C_ + c) * (H_ * W_);

    for (int ph = 0; ph < AH; ++ph) {
        const float h  = y1 + (float)ph * bin_h;
        const float hs = fminf(fmaxf(floorf(h), 0.0f), (float)(H_ - 2));
        const float dh = h - hs;
        const int   yi = (int)hs;
        const bool  vh = (h >= 0.0f) && (h < (float)H_);
        #pragma unroll
        for (int pw = 0; pw < AW; ++pw) {
            const float w  = x1 + (float)pw * bin_w;
            const float ws = fminf(fmaxf(floorf(w), 0.0f), (float)(W_ - 2));
            const float dw = w - ws;
            const int   xi = (int)ws;
            const bool  valid = vh && (w >= 0.0f) && (w < (float)W_);
            const float v00 = fb[(size_t)yi * W_ + xi];
            const float v01 = fb[(size_t)yi * W_ + xi + 1];
            const float v10 = fb[(size_t)(yi + 1) * W_ + xi];
            const float v11 = fb[(size_t)(yi + 1) * W_ + xi + 1];
            float val = v00 * (1.0f - dh) * (1.0f - dw)
                      + v01 * (1.0f - dh) * dw
                      + v10 * dh * (1.0f - dw)
                      + v11 * dh * dw;
            sout[c * KK + ph * AW + pw] = valid ? val : 0.0f;
        }
    }
    __syncthreads();
    float* ob = out + (size_t)r * C_ * KK;
    #pragma unroll 4
    for (int i = threadIdx.x; i < C_ * KK; i += 256) ob[i] = sout[i];
}

extern "C" void kernel_launch(void* const* d_in, const int* in_sizes, int n_in,
                              void* d_out, int out_size, void* d_ws, size_t ws_size,
                              hipStream_t stream) {
    const float* feat  = (const float*)d_in[0];
    const float* rois  = (const float*)d_in[1];
    const float* scale = (const float*)d_in[2];
    float* out = (float*)d_out;

    const int R = in_sizes[1] / 5;                 // 2000
    const int N = in_sizes[0] / (C_ * H_ * W_);    // 2
    const size_t need = (size_t)N * C_ * H_ * W_ * sizeof(unsigned short);

    if (ws_size >= need) {
        unsigned short* tf = (unsigned short*)d_ws;
        dim3 tb(256);
        dim3 tg((H_ * W_) / 64, C_ / 128, N);      // 950 x 2 x 2
        hipLaunchKernelGGL(transpose_nchw_nhwc_bf16, tg, tb, 0, stream, feat, tf);
        hipLaunchKernelGGL(roialign_nhwc_bf16, dim3(R), dim3(512), 0, stream,
                           tf, rois, scale, out);
    } else {
        hipLaunchKernelGGL(roialign_nchw, dim3(R), dim3(256), 0, stream,
                           feat, rois, scale, out);
    }
}